// Round 8
// baseline (254.749 us; speedup 1.0000x reference)
//
#include <hip/hip_runtime.h>
#include <hip/hip_bf16.h>
#include <math.h>

typedef __bf16 bf16_t;
typedef bf16_t bf16x8 __attribute__((ext_vector_type(8)));
typedef float f32x4 __attribute__((ext_vector_type(4)));
typedef float f32x16 __attribute__((ext_vector_type(16)));
typedef unsigned short u16x8 __attribute__((ext_vector_type(8)));

// ---------------- async global->LDS (16B per lane) ----------------
__device__ __forceinline__ void g2l16(const bf16_t* g, bf16_t* l) {
    __builtin_amdgcn_global_load_lds(
        (const __attribute__((address_space(1))) void*)g,
        (__attribute__((address_space(3))) void*)l, 16, 0, 0);
}

// ---------------- prep v2: region-partitioned, branch-hoisted, unrolled -------
__global__ void prep_all(const void* __restrict__ x,
                         const void* __restrict__ cb1, const int* __restrict__ idx1,
                         const void* __restrict__ b1,
                         const void* __restrict__ cb2, const int* __restrict__ idx2,
                         const void* __restrict__ b2,
                         bf16_t* __restrict__ xb, bf16_t* __restrict__ w1b,
                         bf16_t* __restrict__ w2b, float* __restrict__ b1f,
                         float* __restrict__ b2f, int* __restrict__ flag, int M) {
    __shared__ int s_bad;
    const int t = threadIdx.x;
    if (t == 0) s_bad = 0;
    __syncthreads();
    {
        u16x8 v = ((const u16x8*)x)[t];
        int cnt = 0;
#pragma unroll
        for (int j = 0; j < 8; ++j) cnt += (((v[j] >> 7) & 0xFF) >= 0x88);
#pragma unroll
        for (int o = 32; o > 0; o >>= 1) cnt += __shfl_down(cnt, o, 64);
        if ((t & 63) == 0) atomicAdd(&s_bad, cnt);
    }
    __syncthreads();
    const int f32 = (s_bad > 4);
    if (blockIdx.x == 0 && t == 0) flag[0] = f32;

    const int bX = M >> 3;
    const int b = blockIdx.x;

    if (b < bX) {
        const int c0 = b * 1024 + t;
        if (f32) {
            const float4* p = (const float4*)x;
#pragma unroll
            for (int k = 0; k < 4; ++k) {
                const int ci = c0 + k * 256;
                float4 a = p[2 * ci], bb = p[2 * ci + 1];
                bf16x8 o;
                o[0] = (bf16_t)a.x;  o[1] = (bf16_t)a.y;
                o[2] = (bf16_t)a.z;  o[3] = (bf16_t)a.w;
                o[4] = (bf16_t)bb.x; o[5] = (bf16_t)bb.y;
                o[6] = (bf16_t)bb.z; o[7] = (bf16_t)bb.w;
                *(bf16x8*)(xb + (size_t)ci * 8) = o;
            }
        } else {
            const bf16x8* p = (const bf16x8*)x;
#pragma unroll
            for (int k = 0; k < 4; ++k) {
                const int ci = c0 + k * 256;
                *(bf16x8*)(xb + (size_t)ci * 8) = p[ci];
            }
        }
        return;
    }

    int wb = b - bX;
    if (wb < 512) {
        const int c0 = wb * 1024 + t;
        if (f32) {
#pragma unroll
            for (int k = 0; k < 4; ++k) {
                const int ii = c0 + k * 256;
                const int r = ii >> 7;
                const int col = (ii & 127) << 3;
                const int cc = col >> 7;
                const int code = idx1[cc * 4096 + r];
                const float* s = (const float*)cb1 + (size_t)(cc * 256 + code) * 128 + (col & 127);
                float4 a = *(const float4*)s, bb = *(const float4*)(s + 4);
                bf16x8 o;
                o[0] = (bf16_t)a.x;  o[1] = (bf16_t)a.y;
                o[2] = (bf16_t)a.z;  o[3] = (bf16_t)a.w;
                o[4] = (bf16_t)bb.x; o[5] = (bf16_t)bb.y;
                o[6] = (bf16_t)bb.z; o[7] = (bf16_t)bb.w;
                *(bf16x8*)(w1b + (size_t)r * 1024 + col) = o;
            }
        } else {
#pragma unroll
            for (int k = 0; k < 4; ++k) {
                const int ii = c0 + k * 256;
                const int r = ii >> 7;
                const int col = (ii & 127) << 3;
                const int cc = col >> 7;
                const int code = idx1[cc * 4096 + r];
                *(bf16x8*)(w1b + (size_t)r * 1024 + col) =
                    *(const bf16x8*)((const bf16_t*)cb1 + (size_t)(cc * 256 + code) * 128 + (col & 127));
            }
        }
        return;
    }

    wb -= 512;
    {
        const int c0 = wb * 1024 + t;
        if (f32) {
#pragma unroll
            for (int k = 0; k < 4; ++k) {
                const int ii = c0 + k * 256;
                const int r = ii >> 9;
                const int col = (ii & 511) << 3;
                const int cc = col >> 9;
                const int code = idx2[cc * 1024 + r];
                const float* s = (const float*)cb2 + (size_t)(cc * 256 + code) * 512 + (col & 511);
                float4 a = *(const float4*)s, bb = *(const float4*)(s + 4);
                bf16x8 o;
                o[0] = (bf16_t)a.x;  o[1] = (bf16_t)a.y;
                o[2] = (bf16_t)a.z;  o[3] = (bf16_t)a.w;
                o[4] = (bf16_t)bb.x; o[5] = (bf16_t)bb.y;
                o[6] = (bf16_t)bb.z; o[7] = (bf16_t)bb.w;
                *(bf16x8*)(w2b + (size_t)r * 4096 + col) = o;
            }
        } else {
#pragma unroll
            for (int k = 0; k < 4; ++k) {
                const int ii = c0 + k * 256;
                const int r = ii >> 9;
                const int col = (ii & 511) << 3;
                const int cc = col >> 9;
                const int code = idx2[cc * 1024 + r];
                *(bf16x8*)(w2b + (size_t)r * 4096 + col) =
                    *(const bf16x8*)((const bf16_t*)cb2 + (size_t)(cc * 256 + code) * 512 + (col & 511));
            }
        }
    }

    if (wb == 511) {
        for (int g = t; g < 640; g += 256) {
#pragma unroll
            for (int j = 0; j < 8; ++j) {
                const int e = g * 8 + j;
                const void* src = (e < 4096) ? b1 : b2;
                const int k = (e < 4096) ? e : e - 4096;
                const float v = f32 ? ((const float*)src)[k]
                                    : (float)(((const bf16_t*)src)[k]);
                if (e < 4096) b1f[k] = v; else b2f[k] = v;
            }
        }
    }
}

// ---------------- GEMM 128^2, 16x16x32 MFMA (proven; GEMM2 + in-run control) --
template <bool XCDSW, bool GELU, bool DYNOUT>
__global__ __launch_bounds__(256, 2)
void gemm_bt(const bf16_t* __restrict__ A, const bf16_t* __restrict__ Bw,
             const float* __restrict__ bias,
             bf16_t* __restrict__ obf, float* __restrict__ of32,
             int M, int N, int K, const int* __restrict__ flag) {
    __shared__ __attribute__((aligned(16))) bf16_t sA[128 * 64];
    __shared__ __attribute__((aligned(16))) bf16_t sB[128 * 64];

    const int tid = threadIdx.x;

    int bm, bn;
    if (XCDSW) {
        const int l = blockIdx.y * gridDim.x + blockIdx.x;
        const int xcd = l & 7;
        const int i = l >> 3;
        const int per = gridDim.y >> 3;
        bm = (xcd * per + (i % per)) << 7;
        bn = (i / per) << 7;
    } else {
        bm = blockIdx.y << 7;
        bn = blockIdx.x << 7;
    }

    const int row0 = tid >> 3;
    const int kc0 = ((tid & 7) - row0) & 7;
    const bf16_t* gA = A + (size_t)(bm + row0) * K + kc0 * 8;
    const bf16_t* gB = Bw + (size_t)(bn + row0) * K + kc0 * 8;
    bf16_t* lA = sA + tid * 8;
    bf16_t* lB = sB + tid * 8;
    const size_t pskip = (size_t)32 * K;

    const int lane = tid & 63;
    const int wave = tid >> 6;
    const int quad = lane >> 4;
    const int lr = lane & 15;
    const int wm = (wave & 1) << 6;
    const int wn = (wave >> 1) << 6;

    const int arow = wm + lr;
    const int brow = wn + lr;
    const bf16x8* pA0 = (const bf16x8*)(sA + arow * 64 + ((quad + arow) & 7) * 8);
    const bf16x8* pA1 = (const bf16x8*)(sA + arow * 64 + ((quad + 4 + arow) & 7) * 8);
    const bf16x8* pB0 = (const bf16x8*)(sB + brow * 64 + ((quad + brow) & 7) * 8);
    const bf16x8* pB1 = (const bf16x8*)(sB + brow * 64 + ((quad + 4 + brow) & 7) * 8);

    f32x4 acc[4][4] = {};

    for (int k0 = 0; k0 < K; k0 += 64) {
#pragma unroll
        for (int p = 0; p < 4; ++p) g2l16(gA + p * pskip + k0, lA + p * 2048);
#pragma unroll
        for (int p = 0; p < 4; ++p) g2l16(gB + p * pskip + k0, lB + p * 2048);
        __syncthreads();

        bf16x8 af[4], bf[4];
#pragma unroll
        for (int f = 0; f < 4; ++f) { af[f] = pA0[f * 128]; bf[f] = pB0[f * 128]; }
#pragma unroll
        for (int mi = 0; mi < 4; ++mi)
#pragma unroll
            for (int ni = 0; ni < 4; ++ni)
                acc[mi][ni] = __builtin_amdgcn_mfma_f32_16x16x32_bf16(
                    af[mi], bf[ni], acc[mi][ni], 0, 0, 0);
#pragma unroll
        for (int f = 0; f < 4; ++f) { af[f] = pA1[f * 128]; bf[f] = pB1[f * 128]; }
#pragma unroll
        for (int mi = 0; mi < 4; ++mi)
#pragma unroll
            for (int ni = 0; ni < 4; ++ni)
                acc[mi][ni] = __builtin_amdgcn_mfma_f32_16x16x32_bf16(
                    af[mi], bf[ni], acc[mi][ni], 0, 0, 0);
        __syncthreads();
    }

    const int outf32 = DYNOUT ? *flag : 0;
#pragma unroll
    for (int mi = 0; mi < 4; ++mi) {
#pragma unroll
        for (int ni = 0; ni < 4; ++ni) {
            const int n = bn + wn + ni * 16 + lr;
            const float bs = bias[n];
            f32x4 v = acc[mi][ni];
#pragma unroll
            for (int r = 0; r < 4; ++r) {
                const int m = bm + wm + mi * 16 + quad * 4 + r;
                float val = v[r] + bs;
                if (GELU) val = 0.5f * val * (1.0f + erff(val * 0.70710678118654752f));
                const size_t o = (size_t)m * N + n;
                if (DYNOUT) {
                    if (outf32) of32[o] = val;
                    else        obf[o] = (bf16_t)val;
                } else {
                    obf[o] = (bf16_t)val;
                }
            }
        }
    }
}

// ---------------- GEMM 128^2, 32x32x16 MFMA (the experiment: GEMM1) -----------
// Identical staging / swizzle / barriers / grid to gemm_bt; only the MFMA
// shape changes: 16 MFMAs per K-step as 4 subtiles x 4 k-slices of
// mfma_f32_32x32x16_bf16 (~8cy each -> 128cy matrix work/K-step vs 78cy at
// 16x16x32, same ~80cy VALU). A/B frag: row=lane&31, k=(lane>>5)*8+j (family
// pattern of the verified 16x16 layout); C/D: col=lane&31,
// row=(reg&3)+8*(reg>>2)+4*(lane>>5) (HW-verified, m74/m101).
// Chunk-slot rotation: slice s wants global chunk (2s+hi); slot=(chunk+row)&7;
// subtile row offsets (32, wm=64) are ===0 mod 8 -> same slot per lr; distinct
// rows -> distinct slots -> conflict-free, exactly like gemm_bt.
template <bool XCDSW, bool GELU, bool DYNOUT>
__global__ __launch_bounds__(256, 2)
void gemm_bt32(const bf16_t* __restrict__ A, const bf16_t* __restrict__ Bw,
               const float* __restrict__ bias,
               bf16_t* __restrict__ obf, float* __restrict__ of32,
               int M, int N, int K, const int* __restrict__ flag) {
    __shared__ __attribute__((aligned(16))) bf16_t sA[128 * 64];
    __shared__ __attribute__((aligned(16))) bf16_t sB[128 * 64];

    const int tid = threadIdx.x;

    int bm, bn;
    if (XCDSW) {
        const int l = blockIdx.y * gridDim.x + blockIdx.x;
        const int xcd = l & 7;
        const int i = l >> 3;
        const int per = gridDim.y >> 3;
        bm = (xcd * per + (i % per)) << 7;
        bn = (i / per) << 7;
    } else {
        bm = blockIdx.y << 7;
        bn = blockIdx.x << 7;
    }

    const int row0 = tid >> 3;
    const int kc0 = ((tid & 7) - row0) & 7;
    const bf16_t* gA = A + (size_t)(bm + row0) * K + kc0 * 8;
    const bf16_t* gB = Bw + (size_t)(bn + row0) * K + kc0 * 8;
    bf16_t* lA = sA + tid * 8;
    bf16_t* lB = sB + tid * 8;
    const size_t pskip = (size_t)32 * K;

    const int lane = tid & 63;
    const int wave = tid >> 6;
    const int hi = lane >> 5;            // 0..1 (k-half selector)
    const int lr = lane & 31;            // 0..31 (row/col within subtile)
    const int wm = (wave & 1) << 6;
    const int wn = (wave >> 1) << 6;

    const int arow = wm + lr;
    const int brow = wn + lr;
    const bf16_t* pA = sA + arow * 64;
    const bf16_t* pB = sB + brow * 64;
    // slice s reads global chunk (2s+hi); swizzled slot = (chunk + row) & 7.
    // arow&7 == brow&7 == lr&7 -> one slot table serves A and B.
    int off[4];
#pragma unroll
    for (int s = 0; s < 4; ++s) off[s] = (((s << 1) + hi + lr) & 7) << 3;

    f32x16 acc[2][2] = {};

    for (int k0 = 0; k0 < K; k0 += 64) {
#pragma unroll
        for (int p = 0; p < 4; ++p) g2l16(gA + p * pskip + k0, lA + p * 2048);
#pragma unroll
        for (int p = 0; p < 4; ++p) g2l16(gB + p * pskip + k0, lB + p * 2048);
        __syncthreads();

#pragma unroll
        for (int h = 0; h < 2; ++h) {   // two halves: slices {2h, 2h+1}
            bf16x8 aF[2][2], bF[2][2];
#pragma unroll
            for (int si = 0; si < 2; ++si) {
                const int o8 = off[2 * h + si];
#pragma unroll
                for (int mi = 0; mi < 2; ++mi) {
                    aF[mi][si] = *(const bf16x8*)(pA + mi * 2048 + o8);
                    bF[mi][si] = *(const bf16x8*)(pB + mi * 2048 + o8);
                }
            }
#pragma unroll
            for (int si = 0; si < 2; ++si)
#pragma unroll
                for (int mi = 0; mi < 2; ++mi)
#pragma unroll
                    for (int ni = 0; ni < 2; ++ni)
                        acc[mi][ni] = __builtin_amdgcn_mfma_f32_32x32x16_bf16(
                            aF[mi][si], bF[ni][si], acc[mi][ni], 0, 0, 0);
        }
        __syncthreads();
    }

    const int outf32 = DYNOUT ? *flag : 0;
#pragma unroll
    for (int mi = 0; mi < 2; ++mi) {
#pragma unroll
        for (int ni = 0; ni < 2; ++ni) {
            const int n = bn + wn + ni * 32 + lr;
            const float bs = bias[n];
            f32x16 v = acc[mi][ni];
#pragma unroll
            for (int r = 0; r < 16; ++r) {
                const int m = bm + wm + mi * 32 + (r & 3) + ((r >> 2) << 3) + (hi << 2);
                float val = v[r] + bs;
                if (GELU) val = 0.5f * val * (1.0f + erff(val * 0.70710678118654752f));
                const size_t o = (size_t)m * N + n;
                if (DYNOUT) {
                    if (outf32) of32[o] = val;
                    else        obf[o] = (bf16_t)val;
                } else {
                    obf[o] = (bf16_t)val;
                }
            }
        }
    }
}

// ---------------- launch ----------------
extern "C" void kernel_launch(void* const* d_in, const int* in_sizes, int n_in,
                              void* d_out, int out_size, void* d_ws, size_t ws_size,
                              hipStream_t stream) {
    const void* x   = d_in[0];
    const void* cb1 = d_in[1];
    const int*  idx1 = (const int*)d_in[2];
    const void* b1  = d_in[3];
    const void* cb2 = d_in[4];
    const int*  idx2 = (const int*)d_in[5];
    const void* b2  = d_in[6];

    const int D = 1024, H = 4096;
    const int M = in_sizes[0] / D;     // 8192

    char* ws = (char*)d_ws;
    bf16_t* xb  = (bf16_t*)ws;                                   // M*D bf16 (16 MB)
    bf16_t* w1b = (bf16_t*)(ws + (size_t)M * D * 2);             // H*D bf16 (8 MB)
    bf16_t* hb  = (bf16_t*)((char*)w1b + (size_t)H * D * 2);     // M*H bf16 (64 MB)
    bf16_t* w2b = (bf16_t*)((char*)hb + (size_t)M * H * 2);      // D*H bf16 (8 MB)
    float*  b1f = (float*)((char*)w2b + (size_t)D * H * 2);      // H f32
    float*  b2f = b1f + H;                                       // D f32
    int*    flag = (int*)(b2f + D);

    prep_all<<<(M >> 3) + 1024, 256, 0, stream>>>(x, cb1, idx1, b1, cb2, idx2, b2,
                                                  xb, w1b, w2b, b1f, b2f, flag, M);

    // GEMM1: 32x32x16-MFMA variant (the experiment)
    dim3 g1(H / 128, M / 128);   // (32, 64)
    gemm_bt32<false, true, false><<<g1, 256, 0, stream>>>(xb, w1b, b1f, hb, nullptr, M, H, D, flag);

    // GEMM2: unchanged 16x16x32 kernel (in-run control + correctness anchor)
    dim3 g2(D / 128, M / 128);   // (8, 64)
    gemm_bt<true, false, true><<<g2, 256, 0, stream>>>(hb, w2b, b2f,
        (bf16_t*)d_out, (float*)d_out, M, D, H, flag);
}